// Round 6
// baseline (360.972 us; speedup 1.0000x reference)
//
#include <hip/hip_runtime.h>
#include <math.h>

#define NB 256
#define NT 64
#define DIN 512
#define DSAE 4096
#define NK 32

typedef float f32x4 __attribute__((ext_vector_type(4)));
typedef float f32x2 __attribute__((ext_vector_type(2)));

// ---------------- xs[b,d] = sum_t x[b,t,d] + pesum[d]  (pesum recomputed per block) ----------------
__global__ __launch_bounds__(512) void k_xs(const float* __restrict__ x,
                                            float* __restrict__ xs,
                                            float* __restrict__ out) {
    const int b = blockIdx.x, d = threadIdx.x;   // grid NB, block 512
    if (b == 0 && d == 0) out[0] = 0.f;          // loss accumulator zero (k_dec atomicAdds later)
    int j = d >> 1;
    float freq = expf((float)(2 * j) * (-9.210340371976184f / 512.0f));
    float pes = 0.f;
    if (d & 1) {
        for (int t = 0; t < NT; ++t) pes += cosf((float)t * freq);
    } else {
        for (int t = 0; t < NT; ++t) pes += sinf((float)t * freq);
    }
    const float* xp = x + (size_t)b * NT * DIN + d;
    float acc = 0.f;
#pragma unroll 16
    for (int t = 0; t < NT; ++t) acc += xp[(size_t)t * DIN];
    xs[(size_t)b * DIN + d] = acc + pes;
}

// ---------------- pre = xs @ W_enc + b_enc  (256x512 · 512x4096) ----------------
__global__ __launch_bounds__(256) void k_pre(const float* __restrict__ xs,
                                             const float* __restrict__ W,
                                             const float* __restrict__ b_enc,
                                             float* __restrict__ pre) {
    __shared__ float xs_t[DIN][16];   // transposed tile: [d][bb], 32 KB
    const int tid = threadIdx.x;
    const int s = blockIdx.x * 256 + tid;
    const int b0 = blockIdx.y * 16;
    for (int i = tid; i < 16 * DIN; i += 256) {
        int bb = i >> 9, d = i & 511;
        xs_t[d][bb] = xs[(size_t)(b0 + bb) * DIN + d];
    }
    __syncthreads();
    float a[16], c[16];
#pragma unroll
    for (int i = 0; i < 16; ++i) { a[i] = 0.f; c[i] = 0.f; }
    const float* wp = W + s;
#pragma unroll 2
    for (int d = 0; d < DIN; d += 2) {
        float w0 = wp[(size_t)d * DSAE];
        float w1 = wp[(size_t)(d + 1) * DSAE];
        const float4* r0 = (const float4*)&xs_t[d][0];
        const float4* r1 = (const float4*)&xs_t[d + 1][0];
#pragma unroll
        for (int q = 0; q < 4; ++q) {
            float4 u = r0[q];
            a[q*4+0] += u.x * w0; a[q*4+1] += u.y * w0;
            a[q*4+2] += u.z * w0; a[q*4+3] += u.w * w0;
            float4 t2 = r1[q];
            c[q*4+0] += t2.x * w1; c[q*4+1] += t2.y * w1;
            c[q*4+2] += t2.z * w1; c[q*4+3] += t2.w * w1;
        }
    }
    float be = b_enc[s];
#pragma unroll
    for (int bb = 0; bb < 16; ++bb)
        pre[(size_t)(b0 + bb) * DSAE + s] = a[bb] + c[bb] + be;
}

// ---------------- top-32 per row: 1 wave/batch, hierarchical incremental argmax ----------------
__global__ __launch_bounds__(64) void k_topk(const float* __restrict__ pre,
                                             float* __restrict__ z_out,
                                             int* __restrict__ idx_s,
                                             float* __restrict__ zv_s) {
    const int b = blockIdx.x, lane = threadIdx.x;
    const float* pr = pre + (size_t)b * DSAE;
    float* zr = z_out + (size_t)b * DSAE;
    __shared__ float lv[64 * 65];
    __shared__ float lgv[64 * 8];
    __shared__ int   lga[64 * 8];
    for (int j = lane; j < DSAE; j += 64) zr[j] = 0.f;
    const int base = lane * 65;
    float v[64];
#pragma unroll
    for (int j = 0; j < 64; ++j) v[j] = pr[j * 64 + lane];
#pragma unroll
    for (int j = 0; j < 64; ++j) lv[base + j] = v[j];
    float lmax = -INFINITY; int larg = 0;
#pragma unroll
    for (int g = 0; g < 8; ++g) {
        float m = v[g * 8]; int a = g * 8;
#pragma unroll
        for (int t = 1; t < 8; ++t)
            if (v[g * 8 + t] > m) { m = v[g * 8 + t]; a = g * 8 + t; }
        lgv[lane * 8 + g] = m; lga[lane * 8 + g] = a;
        if (m > lmax) { lmax = m; larg = a; }
    }
    __syncthreads();
    int myi = 0; float myv = 0.f;
    for (int k = 0; k < NK; ++k) {
        float bv = lmax; int be = larg * 64 + lane;
#pragma unroll
        for (int off = 32; off >= 1; off >>= 1) {
            float ov = __shfl_down(bv, off);
            int oe = __shfl_down(be, off);
            if (ov > bv || (ov == bv && oe < be)) { bv = ov; be = oe; }
        }
        bv = __shfl(bv, 0); be = __shfl(be, 0);
        if (lane == k) { myi = be; myv = bv > 0.f ? bv : 0.f; }
        if (lane == (be & 63)) {
            int j0 = be >> 6;
            lv[base + j0] = -INFINITY;
            int g0 = j0 >> 3;
            float m = -INFINITY; int a2 = g0 << 3;
            for (int t = 0; t < 8; ++t) {
                float x2 = lv[base + (g0 << 3) + t];
                if (x2 > m) { m = x2; a2 = (g0 << 3) + t; }
            }
            lgv[lane * 8 + g0] = m; lga[lane * 8 + g0] = a2;
            lmax = -INFINITY; larg = 0;
            for (int g = 0; g < 8; ++g) {
                float x2 = lgv[lane * 8 + g];
                if (x2 > lmax) { lmax = x2; larg = lga[lane * 8 + g]; }
            }
        }
    }
    int rank = 0;
#pragma unroll
    for (int j = 0; j < NK; ++j) {
        int oi = __shfl(myi, j);
        if (lane < NK && oi < myi) rank++;
    }
    if (lane < NK) {
        idx_s[b * NK + rank] = myi;
        zv_s[b * NK + rank] = myv;
        zr[myi] = myv;
    }
}

// ---------------- decoder: disjoint column-slice sweep over ALL W_dec rows ----------------
// grid 1024: block owns a 32-float slice of the 32768-float row-space for ALL 256 batches.
// Thread t = batch t, acc[32]. 64 phases of 64 rows: coalesced window load -> LDS (dbuf,
// stride 36 pad), per-thread sorted-merge against window. Every W_dec byte read exactly once.
#define WSTRIDE 36
__global__ __launch_bounds__(256) void k_dec(const float* __restrict__ x,
                                             const float* __restrict__ Wd,
                                             const float* __restrict__ bd,
                                             const int* __restrict__ idx_s,
                                             const float* __restrict__ zv_s,
                                             float* __restrict__ out) {
    const int tid = threadIdx.x;                  // = batch
    const int cbase = blockIdx.x * 32;            // float offset of this block's slice
    __shared__ float buf[2][64 * WSTRIDE];        // 2 x 9 KB (64 rows x 32 floats, padded)

    // accumulator init from b_dec slice (same floats for all threads -> HW broadcast)
    float acc[32];
    {
        const float4* bd4 = (const float4*)(bd + cbase);
#pragma unroll
        for (int q = 0; q < 8; ++q) {
            float4 v = bd4[q];
            acc[q*4+0] = v.x; acc[q*4+1] = v.y; acc[q*4+2] = v.z; acc[q*4+3] = v.w;
        }
    }

    // staging mapping: thread t covers window-row slot_w = t>>2, quads (t&3)*2 + {0,1}
    const int slot_w = tid >> 2;
    const int quad0 = (tid & 3) * 2;
    const float* gsrc = Wd + (size_t)slot_w * (NT * DIN) + cbase + quad0 * 4;

    // merge state over this thread's sorted index list
    const int* myi = idx_s + tid * NK;
    const float* myz = zv_s + tid * NK;
    int p = 0;
    int nexti = myi[0];
    float nextz = myz[0];

    // prologue: stage window 0
    float4 st0 = *(const float4*)(gsrc);
    float4 st1 = *(const float4*)(gsrc + 4);
    {
        float* wb = &buf[0][slot_w * WSTRIDE + quad0 * 4];
        *(float4*)wb = st0;
        *(float4*)(wb + 4) = st1;
    }
    __syncthreads();

    for (int phase = 0; phase < 64; ++phase) {
        // issue next window's loads early (hide HBM latency under compute)
        if (phase < 63) {
            const float* g = gsrc + (size_t)(phase + 1) * 64 * (NT * DIN);
            st0 = *(const float4*)(g);
            st1 = *(const float4*)(g + 4);
        }
        // compute current window
        const int win0 = phase * 64;
        const int winEnd = win0 + 64;
        const float* cb = buf[phase & 1];
        while (nexti < winEnd) {
            const float zk = nextz;
            const float* w = cb + (nexti - win0) * WSTRIDE;
#pragma unroll
            for (int q = 0; q < 8; ++q) {
                float4 wv = *(const float4*)&w[q * 4];
                acc[q*4+0] += zk * wv.x; acc[q*4+1] += zk * wv.y;
                acc[q*4+2] += zk * wv.z; acc[q*4+3] += zk * wv.w;
            }
            ++p;
            if (p < NK) { nexti = myi[p]; nextz = myz[p]; }
            else nexti = 0x7fffffff;
        }
        // write staged regs into the other buffer
        if (phase < 63) {
            float* wb = &buf[(phase + 1) & 1][slot_w * WSTRIDE + quad0 * 4];
            *(float4*)wb = st0;
            *(float4*)(wb + 4) = st1;
        }
        __syncthreads();
    }

    // tail: loss + store x_hat slice (out+1 is only 4B-aligned -> 1/2/4-float split stores)
    const float* xr = x + (size_t)tid * (NT * DIN) + cbase;
    float lsum = 0.f;
#pragma unroll
    for (int e = 0; e < 32; ++e) {
        float xv = __builtin_nontemporal_load(&xr[e]);
        float d = acc[e] - xv;
        lsum += d * d;
    }
    float* xh = out + 1 + (size_t)tid * (NT * DIN) + cbase;
    __builtin_nontemporal_store(acc[0], &xh[0]);
    {
        f32x2 v2; v2.x = acc[1]; v2.y = acc[2];
        __builtin_nontemporal_store(v2, (f32x2*)(xh + 1));
    }
#pragma unroll
    for (int q = 0; q < 7; ++q) {
        f32x4 v4;
        v4.x = acc[3+4*q]; v4.y = acc[4+4*q]; v4.z = acc[5+4*q]; v4.w = acc[6+4*q];
        __builtin_nontemporal_store(v4, (f32x4*)(xh + 3 + 4 * q));
    }
    __builtin_nontemporal_store(acc[31], &xh[31]);

    // block-reduce loss partial
#pragma unroll
    for (int off = 32; off >= 1; off >>= 1) lsum += __shfl_down(lsum, off);
    __shared__ float red[4];
    if ((tid & 63) == 0) red[tid >> 6] = lsum;
    __syncthreads();
    if (tid == 0) {
        float tot = red[0] + red[1] + red[2] + red[3];
        atomicAdd(out, tot * (1.0f / (NB * NT)));
    }
}

extern "C" void kernel_launch(void* const* d_in, const int* in_sizes, int n_in,
                              void* d_out, int out_size, void* d_ws, size_t ws_size,
                              hipStream_t stream) {
    const float* x     = (const float*)d_in[0];
    const float* W_enc = (const float*)d_in[1];
    const float* W_dec = (const float*)d_in[2];
    const float* b_enc = (const float*)d_in[3];
    const float* b_dec = (const float*)d_in[4];
    float* out = (float*)d_out;

    float* ws    = (float*)d_ws;
    float* xs    = ws;                        // 256*512   = 131072
    float* pre   = ws + 131072;               // 256*4096  = 1048576
    int*   idx_s = (int*)(ws + 1179648);      // 256*32 sorted indices
    float* zv_s  = ws + 1187840;              // 256*32 sorted values

    float* z_out = out + 1 + (size_t)NB * NT * DIN;  // z region

    k_xs<<<NB, 512, 0, stream>>>(x, xs, out);
    k_pre<<<dim3(16, 16), 256, 0, stream>>>(xs, W_enc, b_enc, pre);
    k_topk<<<NB, 64, 0, stream>>>(pre, z_out, idx_s, zv_s);
    k_dec<<<1024, 256, 0, stream>>>(x, W_dec, b_dec, idx_s, zv_s, out);
}

// Round 7
// 139.699 us; speedup vs baseline: 2.5839x; 2.5839x over previous
//
#include <hip/hip_runtime.h>
#include <math.h>

#define NB 256
#define NT 64
#define DIN 512
#define DSAE 4096
#define NK 32

typedef float f32x4 __attribute__((ext_vector_type(4)));

// ---------------- xs[b,d] = sum_t x[b,t,d] + pesum[d]  (pesum recomputed per block) ----------------
__global__ __launch_bounds__(512) void k_xs(const float* __restrict__ x,
                                            float* __restrict__ xs,
                                            float* __restrict__ out) {
    const int b = blockIdx.x, d = threadIdx.x;   // grid NB, block 512
    if (b == 0 && d == 0) out[0] = 0.f;          // loss accumulator zero (k_dec atomicAdds later)
    int j = d >> 1;
    float freq = expf((float)(2 * j) * (-9.210340371976184f / 512.0f));
    float pes = 0.f;
    if (d & 1) {
        for (int t = 0; t < NT; ++t) pes += cosf((float)t * freq);
    } else {
        for (int t = 0; t < NT; ++t) pes += sinf((float)t * freq);
    }
    const float* xp = x + (size_t)b * NT * DIN + d;
    float acc = 0.f;
#pragma unroll 16
    for (int t = 0; t < NT; ++t) acc += xp[(size_t)t * DIN];
    xs[(size_t)b * DIN + d] = acc + pes;
}

// ---------------- pre = xs @ W_enc + b_enc  (256x512 · 512x4096) ----------------
// grid (16 s-tiles, 32 b-tiles) = 512 blocks -> 2 blocks/CU -> 2 waves/SIMD (hide FMA latency).
__global__ __launch_bounds__(256) void k_pre(const float* __restrict__ xs,
                                             const float* __restrict__ W,
                                             const float* __restrict__ b_enc,
                                             float* __restrict__ pre) {
    __shared__ float xs_t[DIN][8];   // transposed tile: [d][bb], 16 KB
    const int tid = threadIdx.x;
    const int s = blockIdx.x * 256 + tid;
    const int b0 = blockIdx.y * 8;
    for (int i = tid; i < 8 * DIN; i += 256) {
        int bb = i >> 9, d = i & 511;
        xs_t[d][bb] = xs[(size_t)(b0 + bb) * DIN + d];
    }
    __syncthreads();
    // dual accumulators (even/odd d) for accuracy near the top-k rank boundary
    float a0=0,a1=0,a2=0,a3=0,a4=0,a5=0,a6=0,a7=0;
    float c0=0,c1=0,c2=0,c3=0,c4=0,c5=0,c6=0,c7=0;
    const float* wp = W + s;
#pragma unroll 4
    for (int d = 0; d < DIN; d += 2) {
        float w0 = wp[(size_t)d * DSAE];
        float w1 = wp[(size_t)(d + 1) * DSAE];
        float4 lo0 = *(const float4*)&xs_t[d][0];
        float4 hi0 = *(const float4*)&xs_t[d][4];
        float4 lo1 = *(const float4*)&xs_t[d + 1][0];
        float4 hi1 = *(const float4*)&xs_t[d + 1][4];
        a0 += lo0.x * w0; a1 += lo0.y * w0; a2 += lo0.z * w0; a3 += lo0.w * w0;
        a4 += hi0.x * w0; a5 += hi0.y * w0; a6 += hi0.z * w0; a7 += hi0.w * w0;
        c0 += lo1.x * w1; c1 += lo1.y * w1; c2 += lo1.z * w1; c3 += lo1.w * w1;
        c4 += hi1.x * w1; c5 += hi1.y * w1; c6 += hi1.z * w1; c7 += hi1.w * w1;
    }
    float be = b_enc[s];
    pre[(size_t)(b0 + 0) * DSAE + s] = a0 + c0 + be;
    pre[(size_t)(b0 + 1) * DSAE + s] = a1 + c1 + be;
    pre[(size_t)(b0 + 2) * DSAE + s] = a2 + c2 + be;
    pre[(size_t)(b0 + 3) * DSAE + s] = a3 + c3 + be;
    pre[(size_t)(b0 + 4) * DSAE + s] = a4 + c4 + be;
    pre[(size_t)(b0 + 5) * DSAE + s] = a5 + c5 + be;
    pre[(size_t)(b0 + 6) * DSAE + s] = a6 + c6 + be;
    pre[(size_t)(b0 + 7) * DSAE + s] = a7 + c7 + be;
}

// ---------------- top-32 per row: 1 wave/batch, hierarchical incremental argmax ----------------
__global__ __launch_bounds__(64) void k_topk(const float* __restrict__ pre,
                                             float* __restrict__ z_out,
                                             int* __restrict__ idx_s,
                                             float* __restrict__ zv_s) {
    const int b = blockIdx.x, lane = threadIdx.x;
    const float* pr = pre + (size_t)b * DSAE;
    float* zr = z_out + (size_t)b * DSAE;
    __shared__ float lv[64 * 65];
    __shared__ float lgv[64 * 8];
    __shared__ int   lga[64 * 8];
    for (int j = lane; j < DSAE; j += 64) __builtin_nontemporal_store(0.f, &zr[j]);
    const int base = lane * 65;
    float v[64];
#pragma unroll
    for (int j = 0; j < 64; ++j) v[j] = pr[j * 64 + lane];
#pragma unroll
    for (int j = 0; j < 64; ++j) lv[base + j] = v[j];
    float lmax = -INFINITY; int larg = 0;
#pragma unroll
    for (int g = 0; g < 8; ++g) {
        float m = v[g * 8]; int a = g * 8;
#pragma unroll
        for (int t = 1; t < 8; ++t)
            if (v[g * 8 + t] > m) { m = v[g * 8 + t]; a = g * 8 + t; }
        lgv[lane * 8 + g] = m; lga[lane * 8 + g] = a;
        if (m > lmax) { lmax = m; larg = a; }
    }
    __syncthreads();
    int myi = 0; float myv = 0.f;
    for (int k = 0; k < NK; ++k) {
        float bv = lmax; int be = larg * 64 + lane;
#pragma unroll
        for (int off = 32; off >= 1; off >>= 1) {
            float ov = __shfl_down(bv, off);
            int oe = __shfl_down(be, off);
            if (ov > bv || (ov == bv && oe < be)) { bv = ov; be = oe; }
        }
        bv = __shfl(bv, 0); be = __shfl(be, 0);
        if (lane == k) { myi = be; myv = bv > 0.f ? bv : 0.f; }
        if (lane == (be & 63)) {
            int j0 = be >> 6;
            lv[base + j0] = -INFINITY;
            int g0 = j0 >> 3;
            float m = -INFINITY; int a2 = g0 << 3;
            for (int t = 0; t < 8; ++t) {
                float x2 = lv[base + (g0 << 3) + t];
                if (x2 > m) { m = x2; a2 = (g0 << 3) + t; }
            }
            lgv[lane * 8 + g0] = m; lga[lane * 8 + g0] = a2;
            lmax = -INFINITY; larg = 0;
            for (int g = 0; g < 8; ++g) {
                float x2 = lgv[lane * 8 + g];
                if (x2 > lmax) { lmax = x2; larg = lga[lane * 8 + g]; }
            }
        }
    }
    int rank = 0;
#pragma unroll
    for (int j = 0; j < NK; ++j) {
        int oi = __shfl(myi, j);
        if (lane < NK && oi < myi) rank++;
    }
    if (lane < NK) {
        idx_s[b * NK + rank] = myi;
        zv_s[b * NK + rank] = myv;
        __builtin_nontemporal_store(myv, &zr[myi]);
    }
}

// ---------------- decoder: x_hat = sum_k zv_k * W_dec[i_k] + b_dec ; fused loss ----------------
// R2-exact gather structure (at BW roofline: ~6.4 TB/s effective). Micro: f32x4 nt x-loads,
// per-quad loss (same summation order), scalar nt stores (out+1 only 4B-aligned).
__global__ __launch_bounds__(256) void k_dec(const float* __restrict__ x,
                                             const float* __restrict__ Wd,
                                             const float* __restrict__ bd,
                                             const int* __restrict__ idx_s,
                                             const float* __restrict__ zv_s,
                                             float* __restrict__ out) {
    const int b = blockIdx.y, chunk = blockIdx.x, tid = threadIdx.x;
    __shared__ int si[NK];
    __shared__ float sz[NK];
    if (tid < NK) { si[tid] = idx_s[b * NK + tid]; sz[tid] = zv_s[b * NK + tid]; }
    __syncthreads();
    const int f0 = chunk * 1024 + tid;            // float4 index within 32768-float row
    const float4* bd4 = (const float4*)bd;
    float4 acc0 = bd4[f0];
    float4 acc1 = bd4[f0 + 256];
    float4 acc2 = bd4[f0 + 512];
    float4 acc3 = bd4[f0 + 768];
    for (int k = 0; k < NK; ++k) {
        const float4* w4 = (const float4*)(Wd + (size_t)si[k] * (NT * DIN));
        float zk = sz[k];
        float4 w0 = w4[f0], w1 = w4[f0 + 256], w2 = w4[f0 + 512], w3 = w4[f0 + 768];
        acc0.x += zk * w0.x; acc0.y += zk * w0.y; acc0.z += zk * w0.z; acc0.w += zk * w0.w;
        acc1.x += zk * w1.x; acc1.y += zk * w1.y; acc1.z += zk * w1.z; acc1.w += zk * w1.w;
        acc2.x += zk * w2.x; acc2.y += zk * w2.y; acc2.z += zk * w2.z; acc2.w += zk * w2.w;
        acc3.x += zk * w3.x; acc3.y += zk * w3.y; acc3.z += zk * w3.z; acc3.w += zk * w3.w;
    }
    // x single-use -> nontemporal vector loads; loss per-quad (same add order as before)
    const f32x4* xr4 = (const f32x4*)(x + (size_t)b * (NT * DIN));
    float* xh = out + 1 + (size_t)b * (NT * DIN);   // 4B-aligned only -> scalar stores
    float lsum = 0.f;
    {
        f32x4 xv = __builtin_nontemporal_load(&xr4[f0]);
        float d0 = acc0.x - xv.x, d1 = acc0.y - xv.y, d2 = acc0.z - xv.z, d3 = acc0.w - xv.w;
        lsum += d0 * d0; lsum += d1 * d1; lsum += d2 * d2; lsum += d3 * d3;
        int e = f0 * 4;
        __builtin_nontemporal_store(acc0.x, &xh[e]);   __builtin_nontemporal_store(acc0.y, &xh[e+1]);
        __builtin_nontemporal_store(acc0.z, &xh[e+2]); __builtin_nontemporal_store(acc0.w, &xh[e+3]);
    }
    {
        f32x4 xv = __builtin_nontemporal_load(&xr4[f0 + 256]);
        float d0 = acc1.x - xv.x, d1 = acc1.y - xv.y, d2 = acc1.z - xv.z, d3 = acc1.w - xv.w;
        lsum += d0 * d0; lsum += d1 * d1; lsum += d2 * d2; lsum += d3 * d3;
        int e = (f0 + 256) * 4;
        __builtin_nontemporal_store(acc1.x, &xh[e]);   __builtin_nontemporal_store(acc1.y, &xh[e+1]);
        __builtin_nontemporal_store(acc1.z, &xh[e+2]); __builtin_nontemporal_store(acc1.w, &xh[e+3]);
    }
    {
        f32x4 xv = __builtin_nontemporal_load(&xr4[f0 + 512]);
        float d0 = acc2.x - xv.x, d1 = acc2.y - xv.y, d2 = acc2.z - xv.z, d3 = acc2.w - xv.w;
        lsum += d0 * d0; lsum += d1 * d1; lsum += d2 * d2; lsum += d3 * d3;
        int e = (f0 + 512) * 4;
        __builtin_nontemporal_store(acc2.x, &xh[e]);   __builtin_nontemporal_store(acc2.y, &xh[e+1]);
        __builtin_nontemporal_store(acc2.z, &xh[e+2]); __builtin_nontemporal_store(acc2.w, &xh[e+3]);
    }
    {
        f32x4 xv = __builtin_nontemporal_load(&xr4[f0 + 768]);
        float d0 = acc3.x - xv.x, d1 = acc3.y - xv.y, d2 = acc3.z - xv.z, d3 = acc3.w - xv.w;
        lsum += d0 * d0; lsum += d1 * d1; lsum += d2 * d2; lsum += d3 * d3;
        int e = (f0 + 768) * 4;
        __builtin_nontemporal_store(acc3.x, &xh[e]);   __builtin_nontemporal_store(acc3.y, &xh[e+1]);
        __builtin_nontemporal_store(acc3.z, &xh[e+2]); __builtin_nontemporal_store(acc3.w, &xh[e+3]);
    }

#pragma unroll
    for (int off = 32; off >= 1; off >>= 1) lsum += __shfl_down(lsum, off);
    __shared__ float red[4];
    if ((tid & 63) == 0) red[tid >> 6] = lsum;
    __syncthreads();
    if (tid == 0) {
        float tot = red[0] + red[1] + red[2] + red[3];
        atomicAdd(out, tot * (1.0f / (NB * NT)));
    }
}

extern "C" void kernel_launch(void* const* d_in, const int* in_sizes, int n_in,
                              void* d_out, int out_size, void* d_ws, size_t ws_size,
                              hipStream_t stream) {
    const float* x     = (const float*)d_in[0];
    const float* W_enc = (const float*)d_in[1];
    const float* W_dec = (const float*)d_in[2];
    const float* b_enc = (const float*)d_in[3];
    const float* b_dec = (const float*)d_in[4];
    float* out = (float*)d_out;

    float* ws    = (float*)d_ws;
    float* xs    = ws;                        // 256*512   = 131072
    float* pre   = ws + 131072;               // 256*4096  = 1048576
    int*   idx_s = (int*)(ws + 1179648);      // 256*32 sorted indices
    float* zv_s  = ws + 1187840;              // 256*32 sorted values

    float* z_out = out + 1 + (size_t)NB * NT * DIN;  // z region

    k_xs<<<NB, 512, 0, stream>>>(x, xs, out);
    k_pre<<<dim3(16, 32), 256, 0, stream>>>(xs, W_enc, b_enc, pre);
    k_topk<<<NB, 64, 0, stream>>>(pre, z_out, idx_s, zv_s);
    k_dec<<<dim3(8, NB), 256, 0, stream>>>(x, W_dec, b_dec, idx_s, zv_s, out);
}